// Round 9
// baseline (185.736 us; speedup 1.0000x reference)
//
#include <hip/hip_runtime.h>

// ---------------------------------------------------------------------------
// Self-attention (B=4, N=2048, D=1024) on MI355X — fp16, round 9:
// m201-style 8-phase 256^2 GEMM (4 phases/K-tile, half-tile staging into
// progressively-freed LDS regions, vmcnt(6) once per K-tile) for proj+scores.
// PV keeps the proven 2-phase 128^2 kernel. All plain fp16 (round-8 numerics).
// ---------------------------------------------------------------------------

typedef _Float16 hfx8 __attribute__((ext_vector_type(8)));
typedef _Float16 hfx4 __attribute__((ext_vector_type(4)));
typedef float fx4 __attribute__((ext_vector_type(4)));

__device__ __forceinline__ void load_lds16(const void* g, void* l) {
    __builtin_amdgcn_global_load_lds(
        (const __attribute__((address_space(1))) void*)g,
        (__attribute__((address_space(3))) void*)l, 16, 0, 0);
}

template <int N> __device__ __forceinline__ void vmwait() {
    if constexpr (N == 8) asm volatile("s_waitcnt vmcnt(8)" ::: "memory");
    else if constexpr (N == 6) asm volatile("s_waitcnt vmcnt(6)" ::: "memory");
    else asm volatile("s_waitcnt vmcnt(0)" ::: "memory");
}

// bijective XCD-chunked grid remap (T1, m204). Requires nwg % 8 == 0.
__device__ __forceinline__ void xcd_remap(int& x, int& y, int& z) {
    const int gx = gridDim.x, gy = gridDim.y;
    const int lin = blockIdx.x + gx * (blockIdx.y + gy * blockIdx.z);
    const int cpx = (gx * gy * gridDim.z) >> 3;
    const int w = (lin & 7) * cpx + (lin >> 3);
    x = w % gx;
    y = (w / gx) % gy;
    z = w / (gx * gy);
}

// ---------------------------------------------------------------------------
__global__ __launch_bounds__(256) void convx_kernel(
    const float4* __restrict__ in, _Float16* __restrict__ out)
{
    const int i = blockIdx.x * 256 + threadIdx.x;
    float4 v = in[i];
    hfx4 h;
    h[0] = (_Float16)v.x; h[1] = (_Float16)v.y;
    h[2] = (_Float16)v.z; h[3] = (_Float16)v.w;
    *(hfx4*)&out[(long)i * 4] = h;
}

__global__ __launch_bounds__(256) void convw3_kernel(
    const float4* __restrict__ w0, const float4* __restrict__ w1, const float4* __restrict__ w2,
    _Float16* __restrict__ o0, _Float16* __restrict__ o1, _Float16* __restrict__ o2)
{
    const int wsel = blockIdx.x >> 10;
    const float4* in = wsel == 0 ? w0 : (wsel == 1 ? w1 : w2);
    _Float16* out = wsel == 0 ? o0 : (wsel == 1 ? o1 : o2);
    const int i = (blockIdx.x & 1023) * 256 + threadIdx.x;
    float4 v = in[i];
    hfx4 h;
    h[0] = (_Float16)v.x; h[1] = (_Float16)v.y;
    h[2] = (_Float16)v.z; h[3] = (_Float16)v.w;
    *(hfx4*)&out[(long)i * 4] = h;
}

// ---------------------------------------------------------------------------
// 8-phase 256^2 GEMM (m201 port). BK=64, 512 thr = 8 waves (2M x 4N),
// 128 KB LDS (2 buf x [A 256x64 | B 256x64] fp16).
// Per K-tile t (buf b=t&1), 4 phases q:
//   q reads A-stripe q (rows q*64+wr*32, 4 ds_read_b128; +8 B reads at q0),
//   stages one half-tile: q0 -> A-h1(t+1) into b^1 (A-h1 of b^1 freed after
//   prev tile's q3); q1 -> B-h0(t+2) into b (B freed after q0);
//   q2 -> B-h1(t+2); q3 -> A-h0(t+2) (A-h0 freed after q1).
//   {pre-barrier; lgkmcnt(0); setprio1; 16 MFMA; setprio0;
//    [q3: vmcnt(6) steady / vmcnt(0) tail]; post-barrier}.
// vmcnt(6) proof: outstanding at t.q3 = (t-1).q123(6) + t.q0(2) + t.q123(6)
// = 14 -> drain to 6 drains through t.q0 = last half of tile t+1. Prologue
// stages tile0 full + tile1 {B0,B1,A0} = 14 loads -> vmcnt(6) lands tile0.
// A [M x K] lda; B [N x K] ldb.
// OMODE 0: fp32 out alpha*acc -> outF + z*sCz; B = Bq + z*sBz
// OMODE 1: proj z: 0 Q fp16 [8192][1024], 1 K fp16, 2 V transposed
// ---------------------------------------------------------------------------
template <int OMODE>
__global__ __launch_bounds__(512, 1) void gemm8p(
    const _Float16* __restrict__ A,
    const _Float16* __restrict__ Bq, const _Float16* __restrict__ Bk, const _Float16* __restrict__ Bv,
    const float* __restrict__ bq, const float* __restrict__ bk, const float* __restrict__ bv,
    float* __restrict__ outF, _Float16* __restrict__ oQ, _Float16* __restrict__ oK, _Float16* __restrict__ oV,
    int K, int lda, int ldb, int ldc, float alpha,
    long sAz, long sBz, long sCz)
{
    constexpr int BK = 64;
    __shared__ __attribute__((aligned(16))) _Float16 lds[2][32768]; // 128 KB

    int bx, by, z;
    xcd_remap(bx, by, z);

    A += (long)z * sAz;
    const _Float16* B = (OMODE == 1) ? (z == 0 ? Bq : (z == 1 ? Bk : Bv))
                                     : Bq + (long)z * sBz;

    const int tid = threadIdx.x;
    const int lane = tid & 63;
    const int wv = tid >> 6;
    const int wr = wv >> 2, wc = wv & 3;     // 2M x 4N waves
    const int lr = lane & 15, lk = lane >> 4;

    const long m0 = (long)by * 256;
    const long n0 = (long)bx * 256;

    fx4 acc[4][2][4] = {};                    // [q][j][nf]

    // stage half-tile h (128 rows) of part (0=A,1=B) for K-offset kt into buf b
    auto SH = [&](int kt, int b, int part, int h) {
#pragma unroll
        for (int i = 0; i < 2; ++i) {
            const int g = i * 512 + tid;      // 0..1023
            const int row = h * 128 + (g >> 3);
            const int slot = g & 7;
            const _Float16* src = part ? (B + (n0 + row) * (long)ldb)
                                       : (A + (m0 + row) * (long)lda);
            load_lds16(src + kt + ((slot ^ (row & 7)) << 3),
                       &lds[b][part * 16384 + row * 64 + slot * 8]);
        }
    };

    const int NT = K / BK;
    // prologue: tile0 full {B0,B1,A0,A1}, tile1 {B0,B1,A0}
    SH(0, 0, 1, 0); SH(0, 0, 1, 1); SH(0, 0, 0, 0); SH(0, 0, 0, 1);
    SH(BK, 1, 1, 0); SH(BK, 1, 1, 1); SH(BK, 1, 0, 0);
    vmwait<6>();                              // 14 -> 6: tile0 fully landed
    __builtin_amdgcn_s_barrier();

    const int e = (lr & 7) << 3;              // T2 swizzle offset

    for (int t = 0; t < NT; ++t) {
        const int b = t & 1;
        const _Float16* LA = &lds[b][0];
        const _Float16* LB = &lds[b][16384];

        hfx8 bfr[4][2];
#pragma unroll
        for (int q = 0; q < 4; ++q) {
            if (q == 0) {
#pragma unroll
                for (int nf = 0; nf < 4; ++nf)
#pragma unroll
                    for (int ks = 0; ks < 2; ++ks)
                        bfr[nf][ks] = *(const hfx8*)&LB[(wc * 64 + nf * 16 + lr) * 64 + ((ks * 32 + lk * 8) ^ e)];
            }
            hfx8 afr[2][2];
#pragma unroll
            for (int j = 0; j < 2; ++j)
#pragma unroll
                for (int ks = 0; ks < 2; ++ks)
                    afr[j][ks] = *(const hfx8*)&LA[(q * 64 + wr * 32 + j * 16 + lr) * 64 + ((ks * 32 + lk * 8) ^ e)];

            // half-tile stage (progressive-free schedule)
            if (q == 0)      { if (t + 1 < NT) SH((t + 1) * BK, b ^ 1, 0, 1); }
            else if (q == 1) { if (t + 2 < NT) SH((t + 2) * BK, b, 1, 0); }
            else if (q == 2) { if (t + 2 < NT) SH((t + 2) * BK, b, 1, 1); }
            else             { if (t + 2 < NT) SH((t + 2) * BK, b, 0, 0); }

            __builtin_amdgcn_s_barrier();     // pre-barrier (phase lockstep)
            asm volatile("s_waitcnt lgkmcnt(0)" ::: "memory");
            __builtin_amdgcn_sched_barrier(0);
            __builtin_amdgcn_s_setprio(1);
#pragma unroll
            for (int j = 0; j < 2; ++j)
#pragma unroll
                for (int nf = 0; nf < 4; ++nf)
#pragma unroll
                    for (int ks = 0; ks < 2; ++ks)
                        acc[q][j][nf] = __builtin_amdgcn_mfma_f32_16x16x32_f16(
                            afr[j][ks], bfr[nf][ks], acc[q][j][nf], 0, 0, 0);
            __builtin_amdgcn_s_setprio(0);
            if (q == 3) {
                if (t + 2 < NT) vmwait<6>();      // drains through t.q0
                else if (t + 1 < NT) vmwait<0>(); // tail: t+1 fully landed
            }
            __builtin_amdgcn_s_barrier();     // post-barrier (regions freed)
        }
    }

    // epilogue. rows: q*64 + wr*32 + j*16 + lk*4 + jj ; col: wc*64 + nf*16 + lr
#pragma unroll
    for (int q = 0; q < 4; ++q) {
#pragma unroll
        for (int j = 0; j < 2; ++j) {
#pragma unroll
            for (int nf = 0; nf < 4; ++nf) {
                const long row0 = m0 + q * 64 + wr * 32 + j * 16 + lk * 4;
                const long col = n0 + wc * 64 + nf * 16 + lr;
                if constexpr (OMODE == 0) {
                    float* oz = outF + (long)z * sCz;
#pragma unroll
                    for (int jj = 0; jj < 4; ++jj)
                        oz[(row0 + jj) * (long)ldc + col] = alpha * acc[q][j][nf][jj];
                } else {
                    if (z == 0) {
                        const float bb = bq[col];
#pragma unroll
                        for (int jj = 0; jj < 4; ++jj)
                            oQ[(row0 + jj) * 1024 + col] = (_Float16)(acc[q][j][nf][jj] + bb);
                    } else if (z == 1) {
                        const float bb = bk[col];
#pragma unroll
                        for (int jj = 0; jj < 4; ++jj)
                            oK[(row0 + jj) * 1024 + col] = (_Float16)(acc[q][j][nf][jj] + bb);
                    } else {
                        const float bb = bv[col];
                        hfx4 pk;
#pragma unroll
                        for (int jj = 0; jj < 4; ++jj) pk[jj] = (_Float16)(acc[q][j][nf][jj] + bb);
                        *(hfx4*)&oV[((row0 >> 11) * 1024 + col) * 2048 + (row0 & 2047)] = pk;
                    }
                }
            }
        }
    }
}

// ---------------------------------------------------------------------------
// Proven 2-phase 128x128 pipelined GEMM (rounds 4-8) — used for PV.
// ---------------------------------------------------------------------------
__global__ __launch_bounds__(256, 2) void gemm2(
    const _Float16* __restrict__ A, const _Float16* __restrict__ B,
    float* __restrict__ outF,
    int K, int lda, int ldb, int ldc, float alpha,
    long sAz, long sBz, long sCz)
{
    constexpr int BM = 128, BN = 128, BK = 64;
    constexpr int LPT = 8;

    __shared__ __attribute__((aligned(16))) _Float16 lds[2][(BM + BN) * BK];

    int bx, by, z;
    xcd_remap(bx, by, z);

    A += (long)z * sAz;
    B += (long)z * sBz;

    const int tid = threadIdx.x;
    const int lane = tid & 63;
    const int wv = tid >> 6;
    const int wr = wv >> 1, wc = wv & 1;
    const int lr = lane & 15, lk = lane >> 4;

    const long m0 = (long)by * BM;
    const long n0 = (long)bx * BN;

    fx4 acc[4][4] = {};

    auto STAGE = [&](int kt, int b) {
#pragma unroll
        for (int i = 0; i < LPT; ++i) {
            const int c = i * 256 + tid;
            if (i < 4) {
                const int row = c >> 3, slot = c & 7;
                load_lds16(A + (m0 + row) * (long)lda + kt + ((slot ^ (row & 7)) << 3),
                           &lds[b][c * 8]);
            } else {
                const int c2 = c - 1024;
                const int row = c2 >> 3, slot = c2 & 7;
                load_lds16(B + (n0 + row) * (long)ldb + kt + ((slot ^ (row & 7)) << 3),
                           &lds[b][BM * BK + c2 * 8]);
            }
        }
    };

    const int NT = K / BK;
    STAGE(0, 0);
    STAGE(BK, 1);
    vmwait<8>();
    __builtin_amdgcn_s_barrier();
    __builtin_amdgcn_sched_barrier(0);

    const int rA0 = wr * 64 + lr;
    const int rB0 = wc * 64 + lr;
    const int eA = (rA0 & 7) << 3;
    const int eB = (rB0 & 7) << 3;

    for (int t = 0; t < NT; ++t) {
        const _Float16* LA = &lds[t & 1][0];
        const _Float16* LB = LA + BM * BK;

        hfx8 bfr[4][2];
#pragma unroll
        for (int nf = 0; nf < 4; ++nf)
#pragma unroll
            for (int ks = 0; ks < 2; ++ks)
                bfr[nf][ks] = *(const hfx8*)&LB[(rB0 + nf * 16) * BK + ((ks * 32 + lk * 8) ^ eB)];

#pragma unroll
        for (int q = 0; q < 4; ++q) {
            hfx8 afr[2];
#pragma unroll
            for (int ks = 0; ks < 2; ++ks)
                afr[ks] = *(const hfx8*)&LA[(rA0 + q * 16) * BK + ((ks * 32 + lk * 8) ^ eA)];
            __builtin_amdgcn_s_setprio(1);
#pragma unroll
            for (int nf = 0; nf < 4; ++nf)
#pragma unroll
                for (int ks = 0; ks < 2; ++ks)
                    acc[q][nf] = __builtin_amdgcn_mfma_f32_16x16x32_f16(
                        afr[ks], bfr[nf][ks], acc[q][nf], 0, 0, 0);
            __builtin_amdgcn_s_setprio(0);
        }

        __builtin_amdgcn_s_barrier();
        if (t + 2 < NT) {
            STAGE((t + 2) * BK, t & 1);
            vmwait<8>();
        } else {
            vmwait<0>();
        }
        __builtin_amdgcn_s_barrier();
        __builtin_amdgcn_sched_barrier(0);
    }

#pragma unroll
    for (int mf = 0; mf < 4; ++mf) {
#pragma unroll
        for (int nf = 0; nf < 4; ++nf) {
            const long row0 = m0 + wr * 64 + mf * 16 + lk * 4;
            const long col = n0 + wc * 64 + nf * 16 + lr;
            float* oz = outF + (long)z * sCz;
#pragma unroll
            for (int j = 0; j < 4; ++j)
                oz[(row0 + j) * (long)ldc + col] = alpha * acc[mf][nf][j];
        }
    }
}

// ---------------------------------------------------------------------------
// Row softmax over 2048 fp32, write fp16 probs IN PLACE. One block per row.
// ---------------------------------------------------------------------------
__global__ __launch_bounds__(256) void softmax_kernel(float* __restrict__ S)
{
    const long row = blockIdx.x;
    float* r = S + row * 2048;
    const int t = threadIdx.x;

    float4 v0 = *(const float4*)&r[t * 4];
    float4 v1 = *(const float4*)&r[1024 + t * 4];
    float v[8] = {v0.x, v0.y, v0.z, v0.w, v1.x, v1.y, v1.z, v1.w};

    float mx = v[0];
#pragma unroll
    for (int j = 1; j < 8; ++j) mx = fmaxf(mx, v[j]);
#pragma unroll
    for (int o = 32; o; o >>= 1) mx = fmaxf(mx, __shfl_xor(mx, o, 64));

    __shared__ float redm[4];
    __shared__ float reds[4];
    const int w = t >> 6;
    if ((t & 63) == 0) redm[w] = mx;
    __syncthreads();
    mx = fmaxf(fmaxf(redm[0], redm[1]), fmaxf(redm[2], redm[3]));

    float e[8];
    float s = 0.f;
#pragma unroll
    for (int j = 0; j < 8; ++j) {
        e[j] = __expf(v[j] - mx);
        s += e[j];
    }
#pragma unroll
    for (int o = 32; o; o >>= 1) s += __shfl_xor(s, o, 64);
    if ((t & 63) == 0) reds[w] = s;
    __syncthreads();
    s = reds[0] + reds[1] + reds[2] + reds[3];

    const float inv = 1.0f / s;
    hfx4 p0, p1;
#pragma unroll
    for (int j = 0; j < 4; ++j) {
        p0[j] = (_Float16)(e[j] * inv);
        p1[j] = (_Float16)(e[4 + j] * inv);
    }
    _Float16* pr = (_Float16*)r;
    *(hfx4*)&pr[t * 4] = p0;
    *(hfx4*)&pr[1024 + t * 4] = p1;
}

// ---------------------------------------------------------------------------
extern "C" void kernel_launch(void* const* d_in, const int* in_sizes, int n_in,
                              void* d_out, int out_size, void* d_ws, size_t ws_size,
                              hipStream_t stream)
{
    const float* x  = (const float*)d_in[0];
    const float* Wq = (const float*)d_in[1];
    const float* bq = (const float*)d_in[2];
    const float* Wk = (const float*)d_in[3];
    const float* bk = (const float*)d_in[4];
    const float* Wv = (const float*)d_in[5];
    const float* bv = (const float*)d_in[6];
    float* out = (float*)d_out;

    _Float16* xs  = (_Float16*)d_ws;            // [8192][1024] 16 MB
    _Float16* Wqh = xs + 8192ull * 1024;        // [1024][1024] 2 MB each
    _Float16* Wkh = Wqh + 1024ull * 1024;
    _Float16* Wvh = Wkh + 1024ull * 1024;
    _Float16* Qp  = Wvh + 1024ull * 1024;       // [8192][1024] 16 MB
    _Float16* Ks  = Qp + 8192ull * 1024;        // [8192][1024] 16 MB
    _Float16* Vt  = Ks + 8192ull * 1024;        // [4][1024][2048] 16 MB
    float* S      = (float*)(Vt + 4ull * 1024 * 2048);  // [4][2048][2048] 64 MB

    dim3 blk(256);

    // 1) converts (plain fp16)
    convx_kernel<<<8192, blk, 0, stream>>>((const float4*)x, xs);
    convw3_kernel<<<3072, blk, 0, stream>>>(
        (const float4*)Wq, (const float4*)Wk, (const float4*)Wv, Wqh, Wkh, Wvh);

    // 2) projections: 256^2 8-phase, 4 x 32 x 3 = 384 blocks, K=1024.
    gemm8p<1><<<dim3(4, 32, 3), 512, 0, stream>>>(
        xs, Wqh, Wkh, Wvh, bq, bk, bv,
        nullptr, Qp, Ks, Vt,
        1024, 1024, 1024, 0, 1.0f, 0L, 0L, 0L);

    // 3) scores: Q @ K^T, 256^2 8-phase, 8 x 8 x 4 = 256 blocks, K=1024.
    gemm8p<0><<<dim3(8, 8, 4), 512, 0, stream>>>(
        Qp, Ks, nullptr, nullptr, nullptr, nullptr, nullptr,
        S, nullptr, nullptr, nullptr,
        1024, 1024, 1024, 2048, 1.0f,
        2097152L, 2097152L, 4194304L);

    // 4) softmax (P fp16 in place)
    softmax_kernel<<<2048 * 4, blk, 0, stream>>>(S);

    // 5) PV: P @ Vt^T, proven 2-phase kernel, 8 x 16 x 4 = 512 blocks.
    gemm2<<<dim3(8, 16, 4), blk, 0, stream>>>(
        (const _Float16*)S, Vt, out,
        2048, 4096, 2048, 1024, 0.03125f,
        8388608L, 2097152L, 2097152L);
}